// Round 7
// baseline (280.024 us; speedup 1.0000x reference)
//
#include <hip/hip_runtime.h>

// Problem constants: B=8, flow (B,2,H,W), depth (B,1,H,W), fp32.
constexpr int B  = 8;
constexpr int H  = 720;
constexpr int W  = 1280;
constexpr int HW = H * W;           // 921600
constexpr int N  = B * HW;          // 7372800

// Gather geometry. Inlier band: fx,fy in [-3,3). An inlier source can only
// touch outputs within Chebyshev distance 3.
//
// BIT-EXACT match test (round-2 lesson): the reference floors x2 = fl(gx+fx)
// computed in fp32. We stage the ABSOLUTE fp32 targets (x2, y2) and test
// them against exact integer-valued float boundaries — bit-identical to
// floor attribution. Numerators -fx*w, -fy*w recovered as (gx-x2)*w,
// (gy-y2)*w (error <= ulp/2 ~6e-5; threshold 9.4e-2; rounds 3-6 absmax .016).
// Clamp-edge cases (x2==W-1 / y2==H-1 exactly) go to the outlier pass.
//
// ROUND-3 LESSON: dy loop stays ROLLED (full unroll -> 236 VGPR -> 11% occ).
// ROUND-5: 1col x 4row ownership: 17.5 cand/output, 118 us, VALUBusy 87.5%.
// ROUND-7: 2col x 3row ownership on a 128x12 tile: 72 cand / 6 outputs =
// 12 cand/output (-31%). ax,ay are per-SOURCE so they amortize over all 6
// cells. Parity-split LDS rows (even cols [0,67), odd [67,134)) keep every
// ds_read lane-stride-1 (lane cg reads 4 consecutive float4s per half).
constexpr int TX  = 128;            // tile cols  (1280/128 = 10)
constexpr int TY  = 12;             // tile rows  (720/12   = 60)
constexpr int C   = 3;
constexpr int RWS = TX + 2 * C;     // 134 staged cols (= 2*67)
constexpr int RHS = TY + 2 * C;     // 18 staged rows
constexpr int RNS = RWS * RHS;      // 2412 staged sources (38592 B as float4)
// 256 threads = 64 col-pair groups x 4 row-groups of 3 rows.

// ---------------------------------------------------------------------------
// Zero kernel: 3N floats = 5,529,600 float4s = 21600 blocks x 256 threads.
// ---------------------------------------------------------------------------
__global__ __launch_bounds__(256) void dfp_zero(float* __restrict__ p)
{
    size_t t = ((size_t)blockIdx.x * 256 + threadIdx.x) * 4;
    *(float4*)(p + t) = make_float4(0.f, 0.f, 0.f, 0.f);
}

// ---------------------------------------------------------------------------
// Outlier pass: valid sources NOT handled by the gather fast path (outside
// [-3,3) band OR exact clamp hits). Exact global atomics into zeroed planes.
// ---------------------------------------------------------------------------
__global__ __launch_bounds__(256) void dfp_outlier(
    const float* __restrict__ flow, const float* __restrict__ depth,
    float* __restrict__ pcnt, float* __restrict__ pox, float* __restrict__ poy)
{
    int t = blockIdx.x * 256 + threadIdx.x;
    if (t >= N / 4) return;
    int t4 = t * 4;
    int b  = t4 / HW;
    int p  = t4 - b * HW;
    int i  = p / W;
    int j  = p - i * W;                       // multiple of 4 (W%4==0)

    const float* fxp = flow + b * 2 * HW;
    float4 fx4 = *(const float4*)(fxp + p);
    float4 fy4 = *(const float4*)(fxp + HW + p);
    float fxs[4] = {fx4.x, fx4.y, fx4.z, fx4.w};
    float fys[4] = {fy4.x, fy4.y, fy4.z, fy4.w};

    float* cb = pcnt + b * HW;
    float* xb = pox  + b * HW;
    float* yb = poy  + b * HW;

    #pragma unroll
    for (int e = 0; e < 4; ++e) {
        float fx = fxs[e], fy = fys[e];
        float x2 = (float)(j + e) + fx;
        float y2 = (float)i + fy;
        bool valid = (x2 >= 0.0f) && (x2 <= (float)(W - 1)) &&
                     (y2 >= 0.0f) && (y2 <= (float)(H - 1));
        bool band  = (fx >= -3.0f) && (fx < 3.0f) &&
                     (fy >= -3.0f) && (fy < 3.0f);
        // MUST match dfp_gather's staging predicate exactly.
        bool fast  = band && (x2 < (float)(W - 1)) && (y2 < (float)(H - 1));
        if (valid && !fast) {
            float d  = depth[t4 + e];
            int xL = (int)floorf(x2);
            int yT = (int)floorf(y2);
            int xR = min(xL + 1, W - 1);
            int yB = min(yT + 1, H - 1);
            float w = d, gx = -fx * d, gy = -fy * d;
            int n00 = yT * W + xL, n01 = yT * W + xR;
            int n10 = yB * W + xL, n11 = yB * W + xR;
            unsafeAtomicAdd(&cb[n00], w); unsafeAtomicAdd(&xb[n00], gx); unsafeAtomicAdd(&yb[n00], gy);
            unsafeAtomicAdd(&cb[n01], w); unsafeAtomicAdd(&xb[n01], gx); unsafeAtomicAdd(&yb[n01], gy);
            unsafeAtomicAdd(&cb[n10], w); unsafeAtomicAdd(&xb[n10], gx); unsafeAtomicAdd(&yb[n10], gy);
            unsafeAtomicAdd(&cb[n11], w); unsafeAtomicAdd(&xb[n11], gx); unsafeAtomicAdd(&yb[n11], gy);
        }
    }
}

// ---------------------------------------------------------------------------
// Gather kernel v6: 128x12 tile, each thread owns 2 cols x 3 rows.
// Parity-split float4 staging: row ry stores even source-cols at
// [ry*134 + 0..66], odd at [ry*134 + 67..133]. Thread cg's 8-col window
// (s = 2cg .. 2cg+7) = 4 consecutive even-half + 4 consecutive odd-half
// float4s -> all ds_reads lane-stride-1 (no bank conflicts).
// w=0 encodes dead sources (x2=y2=0 there, so masked-zero FMAs can't NaN).
// ---------------------------------------------------------------------------
__global__ __launch_bounds__(256, 4) void dfp_gather(
    const float* __restrict__ flow, const float* __restrict__ depth,
    const float* __restrict__ pcnt, const float* __restrict__ pox,
    const float* __restrict__ poy, float* __restrict__ out)
{
    __shared__ float4 sq[RNS];       // parity-split rows, 38592 B

    const int tid = threadIdx.x;
    const int tx0 = blockIdx.x * TX;
    const int ty0 = blockIdx.y * TY;
    const int b   = blockIdx.z;

    const float* fxp = flow + b * 2 * HW;
    const float* fyp = fxp + HW;
    const float* dp  = depth + b * HW;

    // ---- Stage tile + halo (parity-split addressing).
    for (int k = tid; k < RNS; k += 256) {
        int ry = k / RWS;                // const divisor -> magic mul
        int s  = k - ry * RWS;           // staged col 0..133
        int gy = ty0 - C + ry;
        int gx = tx0 - C + s;
        float X = 0.f, Y = 0.f, w = 0.f;
        if ((unsigned)gy < (unsigned)H && (unsigned)gx < (unsigned)W) {
            int g = gy * W + gx;
            float fx = fxp[g];
            float fy = fyp[g];
            float x2 = (float)gx + fx;   // EXACTLY the reference's fp32 x2
            float y2 = (float)gy + fy;
            // MUST match dfp_outlier's complement exactly.
            if (fx >= -3.0f && fx < 3.0f && fy >= -3.0f && fy < 3.0f &&
                x2 >= 0.0f && x2 < (float)(W - 1) &&
                y2 >= 0.0f && y2 < (float)(H - 1)) {
                X = x2; Y = y2; w = dp[g];
            }
        }
        int idx = ry * RWS + (s & 1) * (RWS / 2) + (s >> 1);
        sq[idx] = make_float4(X, Y, w, 0.f);
    }
    __syncthreads();

    const int cg   = tid & 63;           // col-pair group (0..63)
    const int rg   = tid >> 6;           // row group (0..3), 3 rows each
    const int oxa0 = tx0 + 2 * cg;       // first owned absolute column

    const float oxaF = (float)oxa0;
    // Column boundaries (exact integer floats): v_k = (X >= oxa0+k).
    const float cm1 = oxaF - 1.0f;
    const float cc0 = oxaF;
    const float cp1 = oxaF + 1.0f;
    const float cp2 = oxaF + 2.0f;

    const int oyb = ty0 + rg * 3;        // first owned absolute row
    const float oybF = (float)oyb;
    // Row boundaries: u_k = (Y >= oyb+k), k = -1..3.
    const float bm1 = oybF - 1.0f;
    const float b0_ = oybF;
    const float b1_ = oybF + 1.0f;
    const float b2_ = oybF + 2.0f;
    const float b3_ = oybF + 3.0f;

    // 2 cols x 3 rows accumulators (named scalars — rule: no runtime-indexed
    // arrays, they go to scratch).
    float c00=0.f,c01=0.f,c02=0.f, c10=0.f,c11=0.f,c12=0.f;
    float x00=0.f,x01=0.f,x02=0.f, x10=0.f,x11=0.f,x12=0.f;
    float y00=0.f,y01=0.f,y02=0.f, y10=0.f,y11=0.f,y12=0.f;

    for (int dy = -C; dy <= 2 + C; ++dy) {           // 9 rows, ROLLED
        const int   rb  = (rg * 3 + dy + C) * RWS;   // staged row base
        const int   be  = rb + cg;                   // even-half base
        const int   bo  = rb + (RWS / 2) + cg;       // odd-half base
        const float gyF = oybF + (float)dy;          // exact source row

        #pragma unroll
        for (int j = 0; j < 4; ++j) {
            // even candidate: source col = oxa0 + (2j-3); odd: oxa0 + (2j-2)
            float4 fe = sq[be + j];
            float4 fo = sq[bo + j];

            #pragma unroll
            for (int pcand = 0; pcand < 2; ++pcand) {
                float4 f   = pcand ? fo : fe;
                float  gxF = oxaF + (float)(2 * j - 3 + pcand);
                const float X = f.x, Y = f.y, w = f.z;

                bool vm1 = (X >= cm1), v0 = (X >= cc0);
                bool v1  = (X >= cp1), v2 = (X >= cp2);
                bool um1 = (Y >= bm1), u0 = (Y >= b0_);
                bool u1  = (Y >= b1_), u2 = (Y >= b2_), u3 = (Y >= b3_);
                bool mc0 = vm1 & !v1;        // X in [oxa0-1, oxa0+1)
                bool mc1 = v0  & !v2;        // X in [oxa0,   oxa0+2)
                bool mr0 = um1 & !u1;        // Y in [oyb-1, oyb+1)
                bool mr1 = u0  & !u2;        // Y in [oyb,   oyb+2)
                bool mr2 = u1  & !u3;        // Y in [oyb+1, oyb+3)

                float ax = gxF - X;          // == -(fx + eps), per-SOURCE
                float ay = gyF - Y;          // == -(fy + eps), per-SOURCE

                float w00 = (mc0 & mr0) ? w : 0.0f;
                float w01 = (mc0 & mr1) ? w : 0.0f;
                float w02 = (mc0 & mr2) ? w : 0.0f;
                float w10 = (mc1 & mr0) ? w : 0.0f;
                float w11 = (mc1 & mr1) ? w : 0.0f;
                float w12 = (mc1 & mr2) ? w : 0.0f;

                c00 += w00; x00 = fmaf(ax, w00, x00); y00 = fmaf(ay, w00, y00);
                c01 += w01; x01 = fmaf(ax, w01, x01); y01 = fmaf(ay, w01, y01);
                c02 += w02; x02 = fmaf(ax, w02, x02); y02 = fmaf(ay, w02, y02);
                c10 += w10; x10 = fmaf(ax, w10, x10); y10 = fmaf(ay, w10, y10);
                c11 += w11; x11 = fmaf(ax, w11, x11); y11 = fmaf(ay, w11, y11);
                c12 += w12; x12 = fmaf(ax, w12, x12); y12 = fmaf(ay, w12, y12);
            }
        }
    }

    // ---- Flush: add outlier planes, normalize, write. float2 per row
    // (oxa0 even -> 8B aligned, coalesced across lanes).
    float* outx = out + b * 2 * HW;
    float* outy = outx + HW;
    const float* cb = pcnt + b * HW;
    const float* xb = pox  + b * HW;
    const float* yb = poy  + b * HW;

    float cA[3] = {c00, c01, c02};
    float cB[3] = {c10, c11, c12};
    float xA[3] = {x00, x01, x02};
    float xB[3] = {x10, x11, x12};
    float yA[3] = {y00, y01, y02};
    float yB[3] = {y10, y11, y12};

    #pragma unroll
    for (int r = 0; r < 3; ++r) {
        int ga = (oyb + r) * W + oxa0;
        float2 c2 = *(const float2*)(cb + ga);
        float2 xv = *(const float2*)(xb + ga);
        float2 yv = *(const float2*)(yb + ga);
        float ca = cA[r] + c2.x;
        float cbv = cB[r] + c2.y;
        float fxa = xA[r] + xv.x;
        float fxb = xB[r] + xv.y;
        float fya = yA[r] + yv.x;
        float fyb = yB[r] + yv.y;
        bool hA = ca  > 0.0f;
        bool hB = cbv > 0.0f;
        float2 ox2 = make_float2(hA ? fxa / ca : 0.0f, hB ? fxb / cbv : 0.0f);
        float2 oy2 = make_float2(hA ? fya / ca : 0.0f, hB ? fyb / cbv : 0.0f);
        *(float2*)(outx + ga) = ox2;
        *(float2*)(outy + ga) = oy2;
    }
}

// ---------------------------------------------------------------------------
// Fallback path (Round-2 proven): used only if ws can't hold 3 planes.
// ---------------------------------------------------------------------------
__global__ __launch_bounds__(256) void dfp_scatter(
    const float* __restrict__ flow, const float* __restrict__ depth,
    float* __restrict__ out, float* __restrict__ count)
{
    int t = blockIdx.x * 256 + threadIdx.x;
    if (t >= N) return;
    int b = t / HW;
    int p = t - b * HW;
    int i = p / W;
    int j = p - i * W;
    const int fbase = b * 2 * HW;
    float fx = flow[fbase + p];
    float fy = flow[fbase + HW + p];
    float d  = depth[t];
    float x2 = (float)j + fx;
    float y2 = (float)i + fy;
    if (!(x2 >= 0.0f && x2 <= (float)(W - 1) &&
          y2 >= 0.0f && y2 <= (float)(H - 1))) return;
    int xL = (int)floorf(x2);
    int yT = (int)floorf(y2);
    int xR = min(xL + 1, W - 1);
    int yB = min(yT + 1, H - 1);
    float w = d, gx = -fx * w, gy = -fy * w;
    float* ox = out + fbase;
    float* oy = out + fbase + HW;
    float* cnt = count + b * HW;
    int n00 = yT * W + xL, n01 = yT * W + xR, n10 = yB * W + xL, n11 = yB * W + xR;
    unsafeAtomicAdd(&cnt[n00], w); unsafeAtomicAdd(&ox[n00], gx); unsafeAtomicAdd(&oy[n00], gy);
    unsafeAtomicAdd(&cnt[n01], w); unsafeAtomicAdd(&ox[n01], gx); unsafeAtomicAdd(&oy[n01], gy);
    unsafeAtomicAdd(&cnt[n10], w); unsafeAtomicAdd(&ox[n10], gx); unsafeAtomicAdd(&oy[n10], gy);
    unsafeAtomicAdd(&cnt[n11], w); unsafeAtomicAdd(&ox[n11], gx); unsafeAtomicAdd(&oy[n11], gy);
}

__global__ __launch_bounds__(256) void dfp_normalize(
    float* __restrict__ out, const float* __restrict__ count)
{
    int t = blockIdx.x * 256 + threadIdx.x;
    if (t >= N / 4) return;
    int t4 = t * 4;
    int b  = t4 / HW;
    int p  = t4 - b * HW;
    float4 c = *(const float4*)(count + t4);
    float* ox = out + b * 2 * HW + p;
    float* oy = ox + HW;
    float4 vx = *(const float4*)ox;
    float4 vy = *(const float4*)oy;
    vx.x = (c.x > 0.0f) ? vx.x / c.x : 0.0f;
    vx.y = (c.y > 0.0f) ? vx.y / c.y : 0.0f;
    vx.z = (c.z > 0.0f) ? vx.z / c.z : 0.0f;
    vx.w = (c.w > 0.0f) ? vx.w / c.w : 0.0f;
    vy.x = (c.x > 0.0f) ? vy.x / c.x : 0.0f;
    vy.y = (c.y > 0.0f) ? vy.y / c.y : 0.0f;
    vy.z = (c.z > 0.0f) ? vy.z / c.z : 0.0f;
    vy.w = (c.w > 0.0f) ? vy.w / c.w : 0.0f;
    *(float4*)ox = vx;
    *(float4*)oy = vy;
}

extern "C" void kernel_launch(void* const* d_in, const int* in_sizes, int n_in,
                              void* d_out, int out_size, void* d_ws, size_t ws_size,
                              hipStream_t stream)
{
    const float* flow  = (const float*)d_in[0];
    const float* depth = (const float*)d_in[1];
    float* out = (float*)d_out;

    if (ws_size >= (size_t)3 * N * sizeof(float)) {
        // Fast path: bit-exact absolute-coordinate gather + exact outlier pass.
        float* pcnt = (float*)d_ws;
        float* pox  = pcnt + N;
        float* poy  = pox + N;
        dfp_zero<<<(3 * N / 4) / 256, 256, 0, stream>>>(pcnt);
        dfp_outlier<<<(N / 4 + 255) / 256, 256, 0, stream>>>(flow, depth, pcnt, pox, poy);
        dim3 grid(W / TX, H / TY, B);   // 10 x 60 x 8 = 4800 blocks
        dfp_gather<<<grid, 256, 0, stream>>>(flow, depth, pcnt, pox, poy, out);
    } else if (ws_size >= (size_t)N * sizeof(float)) {
        // Fallback: proven Round-2 global-atomic path.
        float* count = (float*)d_ws;
        hipMemsetAsync(out,   0, (size_t)2 * N * sizeof(float), stream);
        hipMemsetAsync(count, 0, (size_t)N * sizeof(float),     stream);
        dfp_scatter  <<<(N + 255) / 256,     256, 0, stream>>>(flow, depth, out, count);
        dfp_normalize<<<(N / 4 + 255) / 256, 256, 0, stream>>>(out, count);
    }
    // else: insufficient workspace — cannot run safely.
}

// Round 9
// 257.292 us; speedup vs baseline: 1.0883x; 1.0883x over previous
//
#include <hip/hip_runtime.h>

// Problem constants: B=8, flow (B,2,H,W), depth (B,1,H,W), fp32.
constexpr int B  = 8;
constexpr int H  = 720;
constexpr int W  = 1280;
constexpr int HW = H * W;           // 921600
constexpr int N  = B * HW;          // 7372800

// Gather geometry. Inlier band: fx,fy in [-3,3). An inlier source can only
// touch outputs within Chebyshev distance 3. Gather blocks own 64x16 output
// tiles and scan tile+halo sources.
//
// BIT-EXACT match test (round-2 lesson): the reference floors x2 = fl(gx+fx)
// in fp32. We stage the ABSOLUTE fp32 targets (x2, y2). Round-8 form: test
// RELATIVE coords rx = x2 - oxa, ry = y2 - oyb against inline constants.
// These subtractions are EXACT (operands are multiples of 2^-13 below 2048;
// any such difference fits in 24 significand bits), so the tests are
// bit-identical to floor attribution. Numerators -fx*w, -fy*w recovered as
// (dx - rx)*w, (dy - ry)*w (error <= ulp/2 ~6e-5; threshold 9.4e-2;
// rounds 3-7 absmax 0.016). Clamp edges (x2==W-1 / y2==H-1) -> outlier pass.
//
// ROUND-3 LESSON: dy loop stays ROLLED (full unroll -> 236 VGPR -> 11% occ).
// ROUND-5: this geometry measured 118 us, VALUBusy 87.5%, occ 59%, VGPR 40.
// ROUND-7 LESSON: 2x3-cell ownership DOUBLED inst/cand (63->134); acc ops
// are invariant under ownership splits. Geometry reverted to round-5.
// ROUND-8: single-use-boolean inner body. Emitted code was ~63 inst/cand vs
// ~26 ideal; theory = reused bools (cx across 4 rows, shared t_k row tests)
// force lane-mask materialization. Every bool below is consumed exactly
// once -> v_cmp / s_and / v_cndmask with VCC consumed immediately.
// (Round-8 bench was an infra failure — container acquisition; resubmitted.)
constexpr int TX = 64;              // tile cols  (1280/64 = 20)
constexpr int TY = 16;              // tile rows  (720/16  = 45)
constexpr int C  = 3;
constexpr int RW = TX + 2 * C;      // 70 staged cols
constexpr int RH = TY + 2 * C;      // 22 staged rows
constexpr int RN = RW * RH;         // 1540 staged sources (24640 B as float4)
constexpr int PY = 4;               // output rows per thread
// 256 threads = 64 cols x 4 row-groups; ONE pass covers the 16 rows.

// ---------------------------------------------------------------------------
// Zero kernel: 3N floats = 5,529,600 float4s = 21600 blocks x 256 threads.
// ---------------------------------------------------------------------------
__global__ __launch_bounds__(256) void dfp_zero(float* __restrict__ p)
{
    size_t t = ((size_t)blockIdx.x * 256 + threadIdx.x) * 4;
    *(float4*)(p + t) = make_float4(0.f, 0.f, 0.f, 0.f);
}

// ---------------------------------------------------------------------------
// Outlier pass: valid sources NOT handled by the gather fast path (outside
// [-3,3) band OR exact clamp hits). Exact global atomics into zeroed planes.
// ---------------------------------------------------------------------------
__global__ __launch_bounds__(256) void dfp_outlier(
    const float* __restrict__ flow, const float* __restrict__ depth,
    float* __restrict__ pcnt, float* __restrict__ pox, float* __restrict__ poy)
{
    int t = blockIdx.x * 256 + threadIdx.x;
    if (t >= N / 4) return;
    int t4 = t * 4;
    int b  = t4 / HW;
    int p  = t4 - b * HW;
    int i  = p / W;
    int j  = p - i * W;                       // multiple of 4 (W%4==0)

    const float* fxp = flow + b * 2 * HW;
    float4 fx4 = *(const float4*)(fxp + p);
    float4 fy4 = *(const float4*)(fxp + HW + p);
    float fxs[4] = {fx4.x, fx4.y, fx4.z, fx4.w};
    float fys[4] = {fy4.x, fy4.y, fy4.z, fy4.w};

    float* cb = pcnt + b * HW;
    float* xb = pox  + b * HW;
    float* yb = poy  + b * HW;

    #pragma unroll
    for (int e = 0; e < 4; ++e) {
        float fx = fxs[e], fy = fys[e];
        float x2 = (float)(j + e) + fx;
        float y2 = (float)i + fy;
        bool valid = (x2 >= 0.0f) && (x2 <= (float)(W - 1)) &&
                     (y2 >= 0.0f) && (y2 <= (float)(H - 1));
        bool band  = (fx >= -3.0f) && (fx < 3.0f) &&
                     (fy >= -3.0f) && (fy < 3.0f);
        // MUST match dfp_gather's staging predicate exactly.
        bool fast  = band && (x2 < (float)(W - 1)) && (y2 < (float)(H - 1));
        if (valid && !fast) {
            float d  = depth[t4 + e];
            int xL = (int)floorf(x2);
            int yT = (int)floorf(y2);
            int xR = min(xL + 1, W - 1);
            int yB = min(yT + 1, H - 1);
            float w = d, gx = -fx * d, gy = -fy * d;
            int n00 = yT * W + xL, n01 = yT * W + xR;
            int n10 = yB * W + xL, n11 = yB * W + xR;
            unsafeAtomicAdd(&cb[n00], w); unsafeAtomicAdd(&xb[n00], gx); unsafeAtomicAdd(&yb[n00], gy);
            unsafeAtomicAdd(&cb[n01], w); unsafeAtomicAdd(&xb[n01], gx); unsafeAtomicAdd(&yb[n01], gy);
            unsafeAtomicAdd(&cb[n10], w); unsafeAtomicAdd(&xb[n10], gx); unsafeAtomicAdd(&yb[n10], gy);
            unsafeAtomicAdd(&cb[n11], w); unsafeAtomicAdd(&xb[n11], gx); unsafeAtomicAdd(&yb[n11], gy);
        }
    }
}

// ---------------------------------------------------------------------------
// Gather kernel v7: round-5 geometry + single-use-boolean inner body with
// inline-constant compares on exact relative coordinates.
// Stage (x2, y2, w, 0); w=0 for dead sources (x2=y2=0 there, so masked-zero
// FMAs can't make NaN).
// ---------------------------------------------------------------------------
__global__ __launch_bounds__(256) void dfp_gather(
    const float* __restrict__ flow, const float* __restrict__ depth,
    const float* __restrict__ pcnt, const float* __restrict__ pox,
    const float* __restrict__ poy, float* __restrict__ out)
{
    __shared__ float4 sq[RN];        // (x2, y2, w, pad)  24640 B

    const int tid = threadIdx.x;
    const int tx0 = blockIdx.x * TX;
    const int ty0 = blockIdx.y * TY;
    const int b   = blockIdx.z;

    const float* fxp = flow + b * 2 * HW;
    const float* fyp = fxp + HW;
    const float* dp  = depth + b * HW;

    // ---- Stage tile + halo. w=0 encodes "no contribution here".
    for (int k = tid; k < RN; k += 256) {
        int ry = k / RW;                 // const divisor -> magic mul
        int rx = k - ry * RW;
        int gy = ty0 - C + ry;
        int gx = tx0 - C + rx;
        float X = 0.f, Y = 0.f, w = 0.f;
        if ((unsigned)gy < (unsigned)H && (unsigned)gx < (unsigned)W) {
            int g = gy * W + gx;
            float fx = fxp[g];
            float fy = fyp[g];
            float x2 = (float)gx + fx;   // EXACTLY the reference's fp32 x2
            float y2 = (float)gy + fy;
            // MUST match dfp_outlier's complement exactly.
            if (fx >= -3.0f && fx < 3.0f && fy >= -3.0f && fy < 3.0f &&
                x2 >= 0.0f && x2 < (float)(W - 1) &&
                y2 >= 0.0f && y2 < (float)(H - 1)) {
                X = x2; Y = y2; w = dp[g];
            }
        }
        sq[k] = make_float4(X, Y, w, 0.f);
    }
    __syncthreads();

    const int ox  = tid & 63;            // tile-local column (0..63)
    const int g0  = tid >> 6;            // row group (0..3)
    const int oxa = tx0 + ox;            // absolute output column

    const float oxaF = (float)oxa;

    const int oy0 = g0 * PY;             // tile-local first owned row
    const int oyb = ty0 + oy0;           // absolute row of r=0
    const float oybF = (float)oyb;

    float c0 = 0.f, c1 = 0.f, c2 = 0.f, c3 = 0.f;
    float x0 = 0.f, x1 = 0.f, x2a = 0.f, x3 = 0.f;
    float y0 = 0.f, y1 = 0.f, y2a = 0.f, y3 = 0.f;

    for (int dy = -C; dy <= PY - 1 + C; ++dy) {      // 10 rows, ROLLED
        const int   base = (oy0 + dy + C) * RW + ox; // + (dx+C)
        const float dyF  = (float)dy;
        #pragma unroll
        for (int dx = -C; dx <= C; ++dx) {           // 7 cols
            float4 f = sq[base + dx + C];
            const float X = f.x, Y = f.y, w = f.z;

            // Exact relative coordinates (see header proof).
            float rx = X - oxaF;
            float ry = Y - oybF;

            // Column gate, single-use: floor(X) in {oxa-1,oxa} <=> rx in [-1,1)
            float colw = ((rx >= -1.0f) & (rx < 1.0f)) ? w : 0.0f;

            float ax = (float)dx - rx;   // == -(fx + eps), per-source
            float ay = dyF - ry;         // == -(fy + eps), per-source

            // Row gates: fresh cmps per row, every bool consumed once.
            float w0 = ((ry >= -1.0f) & (ry < 1.0f)) ? colw : 0.0f;
            float w1 = ((ry >=  0.0f) & (ry < 2.0f)) ? colw : 0.0f;
            float w2 = ((ry >=  1.0f) & (ry < 3.0f)) ? colw : 0.0f;
            float w3 = ((ry >=  2.0f) & (ry < 4.0f)) ? colw : 0.0f;

            c0 += w0;  x0  = fmaf(ax, w0, x0 );  y0  = fmaf(ay, w0, y0 );
            c1 += w1;  x1  = fmaf(ax, w1, x1 );  y1  = fmaf(ay, w1, y1 );
            c2 += w2;  x2a = fmaf(ax, w2, x2a);  y2a = fmaf(ay, w2, y2a);
            c3 += w3;  x3  = fmaf(ax, w3, x3 );  y3  = fmaf(ay, w3, y3 );
        }
    }

    // ---- Flush: add outlier planes, normalize, write. Coalesced (lane=ox).
    float* outx = out + b * 2 * HW;
    float* outy = outx + HW;
    const float* cb = pcnt + b * HW;
    const float* xb = pox  + b * HW;
    const float* yb = poy  + b * HW;

    float cc[PY] = {c0, c1, c2, c3};
    float vx[PY] = {x0, x1, x2a, x3};
    float vy[PY] = {y0, y1, y2a, y3};
    #pragma unroll
    for (int r = 0; r < PY; ++r) {
        int ga = (oyb + r) * W + oxa;
        float c  = cc[r] + cb[ga];
        float fx = vx[r] + xb[ga];
        float fy = vy[r] + yb[ga];
        bool has = c > 0.0f;
        outx[ga] = has ? fx / c : 0.0f;
        outy[ga] = has ? fy / c : 0.0f;
    }
}

// ---------------------------------------------------------------------------
// Fallback path (Round-2 proven): used only if ws can't hold 3 planes.
// ---------------------------------------------------------------------------
__global__ __launch_bounds__(256) void dfp_scatter(
    const float* __restrict__ flow, const float* __restrict__ depth,
    float* __restrict__ out, float* __restrict__ count)
{
    int t = blockIdx.x * 256 + threadIdx.x;
    if (t >= N) return;
    int b = t / HW;
    int p = t - b * HW;
    int i = p / W;
    int j = p - i * W;
    const int fbase = b * 2 * HW;
    float fx = flow[fbase + p];
    float fy = flow[fbase + HW + p];
    float d  = depth[t];
    float x2 = (float)j + fx;
    float y2 = (float)i + fy;
    if (!(x2 >= 0.0f && x2 <= (float)(W - 1) &&
          y2 >= 0.0f && y2 <= (float)(H - 1))) return;
    int xL = (int)floorf(x2);
    int yT = (int)floorf(y2);
    int xR = min(xL + 1, W - 1);
    int yB = min(yT + 1, H - 1);
    float w = d, gx = -fx * w, gy = -fy * w;
    float* ox = out + fbase;
    float* oy = out + fbase + HW;
    float* cnt = count + b * HW;
    int n00 = yT * W + xL, n01 = yT * W + xR, n10 = yB * W + xL, n11 = yB * W + xR;
    unsafeAtomicAdd(&cnt[n00], w); unsafeAtomicAdd(&ox[n00], gx); unsafeAtomicAdd(&oy[n00], gy);
    unsafeAtomicAdd(&cnt[n01], w); unsafeAtomicAdd(&ox[n01], gx); unsafeAtomicAdd(&oy[n01], gy);
    unsafeAtomicAdd(&cnt[n10], w); unsafeAtomicAdd(&ox[n10], gx); unsafeAtomicAdd(&oy[n10], gy);
    unsafeAtomicAdd(&cnt[n11], w); unsafeAtomicAdd(&ox[n11], gx); unsafeAtomicAdd(&oy[n11], gy);
}

__global__ __launch_bounds__(256) void dfp_normalize(
    float* __restrict__ out, const float* __restrict__ count)
{
    int t = blockIdx.x * 256 + threadIdx.x;
    if (t >= N / 4) return;
    int t4 = t * 4;
    int b  = t4 / HW;
    int p  = t4 - b * HW;
    float4 c = *(const float4*)(count + t4);
    float* ox = out + b * 2 * HW + p;
    float* oy = ox + HW;
    float4 vx = *(const float4*)ox;
    float4 vy = *(const float4*)oy;
    vx.x = (c.x > 0.0f) ? vx.x / c.x : 0.0f;
    vx.y = (c.y > 0.0f) ? vx.y / c.y : 0.0f;
    vx.z = (c.z > 0.0f) ? vx.z / c.z : 0.0f;
    vx.w = (c.w > 0.0f) ? vx.w / c.w : 0.0f;
    vy.x = (c.x > 0.0f) ? vy.x / c.x : 0.0f;
    vy.y = (c.y > 0.0f) ? vy.y / c.y : 0.0f;
    vy.z = (c.z > 0.0f) ? vy.z / c.z : 0.0f;
    vy.w = (c.w > 0.0f) ? vy.w / c.w : 0.0f;
    *(float4*)ox = vx;
    *(float4*)oy = vy;
}

extern "C" void kernel_launch(void* const* d_in, const int* in_sizes, int n_in,
                              void* d_out, int out_size, void* d_ws, size_t ws_size,
                              hipStream_t stream)
{
    const float* flow  = (const float*)d_in[0];
    const float* depth = (const float*)d_in[1];
    float* out = (float*)d_out;

    if (ws_size >= (size_t)3 * N * sizeof(float)) {
        // Fast path: bit-exact absolute-coordinate gather + exact outlier pass.
        float* pcnt = (float*)d_ws;
        float* pox  = pcnt + N;
        float* poy  = pox + N;
        dfp_zero<<<(3 * N / 4) / 256, 256, 0, stream>>>(pcnt);
        dfp_outlier<<<(N / 4 + 255) / 256, 256, 0, stream>>>(flow, depth, pcnt, pox, poy);
        dim3 grid(W / TX, H / TY, B);   // 20 x 45 x 8 = 7200 blocks
        dfp_gather<<<grid, 256, 0, stream>>>(flow, depth, pcnt, pox, poy, out);
    } else if (ws_size >= (size_t)N * sizeof(float)) {
        // Fallback: proven Round-2 global-atomic path.
        float* count = (float*)d_ws;
        hipMemsetAsync(out,   0, (size_t)2 * N * sizeof(float), stream);
        hipMemsetAsync(count, 0, (size_t)N * sizeof(float),     stream);
        dfp_scatter  <<<(N + 255) / 256,     256, 0, stream>>>(flow, depth, out, count);
        dfp_normalize<<<(N / 4 + 255) / 256, 256, 0, stream>>>(out, count);
    }
    // else: insufficient workspace — cannot run safely.
}